// Round 1
// baseline (223.854 us; speedup 1.0000x reference)
//
#include <hip/hip_runtime.h>
#include <math.h>

#define NG 1024
#define NC 2
#define HH 224
#define WW 224
#define EPS2D 0.3f
#define ALPHA_MIN (1.0f/255.0f)
#define ALPHA_MAX 0.999f

// Workspace layout (floats):
//   Region A (unsorted, per cam stride 10*NG): z,u,v,ia,ib,id,o,r,g,b
//   Region B at offset 2*10*NG (sorted, per cam stride 9*NG): u,v,ia,ib,id,o,r,g,b
#define A_STRIDE (10*NG)
#define B_BASE   (2*A_STRIDE)
#define B_STRIDE (9*NG)

__global__ void prep_kernel(const float* __restrict__ w2cs, const float* __restrict__ Ks,
                            const float* __restrict__ xyz, const float* __restrict__ rgb,
                            const float* __restrict__ opac, const float* __restrict__ scale,
                            const float* __restrict__ rot, float* __restrict__ ws) {
    int idx = blockIdx.x * blockDim.x + threadIdx.x;
    if (idx >= NC * NG) return;
    int cam = idx >> 10;
    int g   = idx & (NG - 1);

    // quaternion -> rotation
    float qw = rot[g*4+0], qx = rot[g*4+1], qy = rot[g*4+2], qz = rot[g*4+3];
    float qn = rsqrtf(qw*qw + qx*qx + qy*qy + qz*qz);
    qw *= qn; qx *= qn; qy *= qn; qz *= qn;
    float r00 = 1.f - 2.f*(qy*qy + qz*qz), r01 = 2.f*(qx*qy - qw*qz), r02 = 2.f*(qx*qz + qw*qy);
    float r10 = 2.f*(qx*qy + qw*qz), r11 = 1.f - 2.f*(qx*qx + qz*qz), r12 = 2.f*(qy*qz - qw*qx);
    float r20 = 2.f*(qx*qz - qw*qy), r21 = 2.f*(qy*qz + qw*qx), r22 = 1.f - 2.f*(qx*qx + qy*qy);

    float sx = scale[g*3+0], sy = scale[g*3+1], sz = scale[g*3+2];
    float m00 = r00*sx, m01 = r01*sy, m02 = r02*sz;
    float m10 = r10*sx, m11 = r11*sy, m12 = r12*sz;
    float m20 = r20*sx, m21 = r21*sy, m22 = r22*sz;
    // cov3d = M M^T (symmetric)
    float c00 = m00*m00 + m01*m01 + m02*m02;
    float c01 = m00*m10 + m01*m11 + m02*m12;
    float c02 = m00*m20 + m01*m21 + m02*m22;
    float c11 = m10*m10 + m11*m11 + m12*m12;
    float c12 = m10*m20 + m11*m21 + m12*m22;
    float c22 = m20*m20 + m21*m21 + m22*m22;

    const float* vm = w2cs + cam*16;
    float R00 = vm[0],  R01 = vm[1],  R02 = vm[2],  t0 = vm[3];
    float R10 = vm[4],  R11 = vm[5],  R12 = vm[6],  t1 = vm[7];
    float R20 = vm[8],  R21 = vm[9],  R22 = vm[10], t2 = vm[11];

    float X = xyz[g*3], Y = xyz[g*3+1], Z = xyz[g*3+2];
    float px = R00*X + R01*Y + R02*Z + t0;
    float py = R10*X + R11*Y + R12*Z + t1;
    float pz = R20*X + R21*Y + R22*Z + t2;
    float rz = 1.f / pz;

    const float* Kc = Ks + cam*9;
    float fx = Kc[0], cx = Kc[2], fy = Kc[4], cy = Kc[5];
    float limx = 1.3f * (0.5f * (float)WW / fx);
    float limy = 1.3f * (0.5f * (float)HH / fy);
    float txc = pz * fminf(fmaxf(px*rz, -limx), limx);
    float tyc = pz * fminf(fmaxf(py*rz, -limy), limy);

    // cov_cam = R * cov3d * R^T  (V = R*C, then V*R^T)
    float v00 = R00*c00 + R01*c01 + R02*c02;
    float v01 = R00*c01 + R01*c11 + R02*c12;
    float v02 = R00*c02 + R01*c12 + R02*c22;
    float v10 = R10*c00 + R11*c01 + R12*c02;
    float v11 = R10*c01 + R11*c11 + R12*c12;
    float v12 = R10*c02 + R11*c12 + R12*c22;
    float v20 = R20*c00 + R21*c01 + R22*c02;
    float v21 = R20*c01 + R21*c11 + R22*c12;
    float v22 = R20*c02 + R21*c12 + R22*c22;
    float cc00 = v00*R00 + v01*R01 + v02*R02;
    float cc01 = v00*R10 + v01*R11 + v02*R12;
    float cc02 = v00*R20 + v01*R21 + v02*R22;
    float cc11 = v10*R10 + v11*R11 + v12*R12;
    float cc12 = v10*R20 + v11*R21 + v12*R22;
    float cc22 = v20*R20 + v21*R21 + v22*R22;

    float j00 = fx*rz, j02 = -fx*txc*rz*rz;
    float j11 = fy*rz, j12 = -fy*tyc*rz*rz;
    float a = j00*j00*cc00 + 2.f*j00*j02*cc02 + j02*j02*cc22 + EPS2D;
    float b = j00*j11*cc01 + j00*j12*cc02 + j02*j11*cc12 + j02*j12*cc22;
    float d = j11*j11*cc11 + 2.f*j11*j12*cc12 + j12*j12*cc22 + EPS2D;
    float det = a*d - b*b;

    bool valid = (pz > 0.01f) && (pz < 100.f) && (det > 0.f);
    float idet = valid ? (1.f / det) : 0.f;
    float ia  = d * idet;
    float ib  = -b * idet;
    float id_ = a * idet;
    float u = valid ? (fx*px*rz + cx) : 0.f;
    float v = valid ? (fy*py*rz + cy) : 0.f;
    float o = valid ? opac[g] : 0.f;

    float* A = ws + cam * A_STRIDE;
    A[0*NG + g] = pz;
    A[1*NG + g] = u;
    A[2*NG + g] = v;
    A[3*NG + g] = ia;
    A[4*NG + g] = ib;
    A[5*NG + g] = id_;
    A[6*NG + g] = o;
    A[7*NG + g] = rgb[g*3+0];
    A[8*NG + g] = rgb[g*3+1];
    A[9*NG + g] = rgb[g*3+2];
}

// One block of 1024 threads per camera: bitonic sort by z, then gather into sorted SoA.
__global__ void sort_kernel(float* __restrict__ ws) {
    __shared__ float key[NG];
    __shared__ int   sidx[NG];
    int t = threadIdx.x;
    int cam = blockIdx.x;
    const float* A = ws + cam * A_STRIDE;
    key[t] = A[t];        // z
    sidx[t] = t;
    __syncthreads();
    for (int k = 2; k <= NG; k <<= 1) {
        for (int j = k >> 1; j > 0; j >>= 1) {
            int ixj = t ^ j;
            if (ixj > t) {
                bool up = ((t & k) == 0);
                float ka = key[t], kb = key[ixj];
                if ((ka > kb) == up) {
                    key[t] = kb; key[ixj] = ka;
                    int tmp = sidx[t]; sidx[t] = sidx[ixj]; sidx[ixj] = tmp;
                }
            }
            __syncthreads();
        }
    }
    int src = sidx[t];
    float* B = ws + B_BASE + cam * B_STRIDE;
    #pragma unroll
    for (int arr = 0; arr < 9; arr++) {
        B[arr*NG + t] = A[(arr+1)*NG + src];
    }
}

#define CHUNK 256

__global__ __launch_bounds__(256) void render_kernel(const float* __restrict__ ws,
                                                     float* __restrict__ out) {
    const int cam = blockIdx.y;
    const float* B = ws + B_BASE + cam * B_STRIDE;
    __shared__ float4 sA[CHUNK];  // u, v, ia, ib
    __shared__ float4 sB[CHUNK];  // id, o, r, g
    __shared__ float  sC[CHUNK];  // b

    int tid = threadIdx.x;
    int p = blockIdx.x * 256 + tid;
    float pxl = (float)(p % WW) + 0.5f;
    float pyl = (float)(p / WW) + 0.5f;

    float T = 1.f, cr = 0.f, cg = 0.f, cb = 0.f;

    for (int base = 0; base < NG; base += CHUNK) {
        sA[tid] = make_float4(B[0*NG + base + tid], B[1*NG + base + tid],
                              B[2*NG + base + tid], B[3*NG + base + tid]);
        sB[tid] = make_float4(B[4*NG + base + tid], B[5*NG + base + tid],
                              B[6*NG + base + tid], B[7*NG + base + tid]);
        sC[tid] = B[8*NG + base + tid];
        __syncthreads();

        for (int i = 0; i < CHUNK; i++) {
            float4 ga = sA[i];
            float4 gb = sB[i];
            float dx = ga.x - pxl;
            float dy = ga.y - pyl;
            float sigma = 0.5f*(ga.z*dx*dx + gb.x*dy*dy) + ga.w*dx*dy;
            if (sigma >= 0.f) {
                float alpha = fminf(gb.y * __expf(-sigma), ALPHA_MAX);
                if (alpha > ALPHA_MIN) {
                    float w = alpha * T;
                    cr += w * gb.z;
                    cg += w * gb.w;
                    cb += w * sC[i];
                    T *= (1.f - alpha);
                }
            }
        }
        if (__syncthreads_and(T < 1e-4f)) break;
    }

    // img = accumulated + T * bg (bg = 1,1,1)
    float* img = out + cam * (HH*WW*3) + p*3;
    img[0] = cr + T;
    img[1] = cg + T;
    img[2] = cb + T;
    out[NC*HH*WW*3 + cam*(HH*WW) + p] = 1.f - T;
}

extern "C" void kernel_launch(void* const* d_in, const int* in_sizes, int n_in,
                              void* d_out, int out_size, void* d_ws, size_t ws_size,
                              hipStream_t stream) {
    const float* w2cs  = (const float*)d_in[0];
    const float* Ks    = (const float*)d_in[1];
    const float* xyz   = (const float*)d_in[2];
    const float* rgb   = (const float*)d_in[3];
    const float* opac  = (const float*)d_in[4];
    const float* scale = (const float*)d_in[5];
    const float* rot   = (const float*)d_in[6];
    float* out = (float*)d_out;
    float* ws  = (float*)d_ws;

    prep_kernel<<<dim3((NC*NG + 255)/256), 256, 0, stream>>>(w2cs, Ks, xyz, rgb, opac, scale, rot, ws);
    sort_kernel<<<dim3(NC), NG, 0, stream>>>(ws);
    render_kernel<<<dim3((HH*WW)/256, NC), 256, 0, stream>>>(ws, out);
}

// Round 2
// 182.633 us; speedup vs baseline: 1.2257x; 1.2257x over previous
//
#include <hip/hip_runtime.h>
#include <math.h>

#define NG 1024
#define NC 2
#define HH 224
#define WW 224
#define EPS2D 0.3f
#define ALPHA_MIN (1.0f/255.0f)
#define ALPHA_MAX 0.999f

// Workspace layout (float units):
//   zbuf  at Z_OFF    : NC*NG
//   Atmp  at ATMP_OFF : NC*NG*12 (AoS: u,v,ia,ib,id,o,r,g,b,pad,pad,pad)
//   B     at B_OFF    : NC*NG*12 (depth-sorted AoS, same layout)
#define Z_OFF    0
#define ATMP_OFF (NC*NG)
#define B_OFF    (ATMP_OFF + NC*NG*12)

__global__ void prep_kernel(const float* __restrict__ w2cs, const float* __restrict__ Ks,
                            const float* __restrict__ xyz, const float* __restrict__ rgb,
                            const float* __restrict__ opac, const float* __restrict__ scale,
                            const float* __restrict__ rot, float* __restrict__ ws) {
    int idx = blockIdx.x * blockDim.x + threadIdx.x;
    if (idx >= NC * NG) return;
    int cam = idx >> 10;
    int g   = idx & (NG - 1);

    float qw = rot[g*4+0], qx = rot[g*4+1], qy = rot[g*4+2], qz = rot[g*4+3];
    float qn = rsqrtf(qw*qw + qx*qx + qy*qy + qz*qz);
    qw *= qn; qx *= qn; qy *= qn; qz *= qn;
    float r00 = 1.f - 2.f*(qy*qy + qz*qz), r01 = 2.f*(qx*qy - qw*qz), r02 = 2.f*(qx*qz + qw*qy);
    float r10 = 2.f*(qx*qy + qw*qz), r11 = 1.f - 2.f*(qx*qx + qz*qz), r12 = 2.f*(qy*qz - qw*qx);
    float r20 = 2.f*(qx*qz - qw*qy), r21 = 2.f*(qy*qz + qw*qx), r22 = 1.f - 2.f*(qx*qx + qy*qy);

    float sx = scale[g*3+0], sy = scale[g*3+1], sz = scale[g*3+2];
    float m00 = r00*sx, m01 = r01*sy, m02 = r02*sz;
    float m10 = r10*sx, m11 = r11*sy, m12 = r12*sz;
    float m20 = r20*sx, m21 = r21*sy, m22 = r22*sz;
    float c00 = m00*m00 + m01*m01 + m02*m02;
    float c01 = m00*m10 + m01*m11 + m02*m12;
    float c02 = m00*m20 + m01*m21 + m02*m22;
    float c11 = m10*m10 + m11*m11 + m12*m12;
    float c12 = m10*m20 + m11*m21 + m12*m22;
    float c22 = m20*m20 + m21*m21 + m22*m22;

    const float* vm = w2cs + cam*16;
    float R00 = vm[0],  R01 = vm[1],  R02 = vm[2],  t0 = vm[3];
    float R10 = vm[4],  R11 = vm[5],  R12 = vm[6],  t1 = vm[7];
    float R20 = vm[8],  R21 = vm[9],  R22 = vm[10], t2 = vm[11];

    float X = xyz[g*3], Y = xyz[g*3+1], Z = xyz[g*3+2];
    float px = R00*X + R01*Y + R02*Z + t0;
    float py = R10*X + R11*Y + R12*Z + t1;
    float pz = R20*X + R21*Y + R22*Z + t2;
    float rz = 1.f / pz;

    const float* Kc = Ks + cam*9;
    float fx = Kc[0], cx = Kc[2], fy = Kc[4], cy = Kc[5];
    float limx = 1.3f * (0.5f * (float)WW / fx);
    float limy = 1.3f * (0.5f * (float)HH / fy);
    float txc = pz * fminf(fmaxf(px*rz, -limx), limx);
    float tyc = pz * fminf(fmaxf(py*rz, -limy), limy);

    float v00 = R00*c00 + R01*c01 + R02*c02;
    float v01 = R00*c01 + R01*c11 + R02*c12;
    float v02 = R00*c02 + R01*c12 + R02*c22;
    float v10 = R10*c00 + R11*c01 + R12*c02;
    float v11 = R10*c01 + R11*c11 + R12*c12;
    float v12 = R10*c02 + R11*c12 + R12*c22;
    float v20 = R20*c00 + R21*c01 + R22*c02;
    float v21 = R20*c01 + R21*c11 + R22*c12;
    float v22 = R20*c02 + R21*c12 + R22*c22;
    float cc00 = v00*R00 + v01*R01 + v02*R02;
    float cc01 = v00*R10 + v01*R11 + v02*R12;
    float cc02 = v00*R20 + v01*R21 + v02*R22;
    float cc11 = v10*R10 + v11*R11 + v12*R12;
    float cc12 = v10*R20 + v11*R21 + v12*R22;
    float cc22 = v20*R20 + v21*R21 + v22*R22;

    float j00 = fx*rz, j02 = -fx*txc*rz*rz;
    float j11 = fy*rz, j12 = -fy*tyc*rz*rz;
    float a = j00*j00*cc00 + 2.f*j00*j02*cc02 + j02*j02*cc22 + EPS2D;
    float b = j00*j11*cc01 + j00*j12*cc02 + j02*j11*cc12 + j02*j12*cc22;
    float d = j11*j11*cc11 + 2.f*j11*j12*cc12 + j12*j12*cc22 + EPS2D;
    float det = a*d - b*b;

    bool valid = (pz > 0.01f) && (pz < 100.f) && (det > 0.f);
    float idet = valid ? (1.f / det) : 0.f;
    float ia  = d * idet;
    float ib  = -b * idet;
    float id_ = a * idet;
    float u = valid ? (fx*px*rz + cx) : 0.f;
    float v = valid ? (fy*py*rz + cy) : 0.f;
    float o = valid ? opac[g] : 0.f;

    ws[Z_OFF + cam*NG + g] = pz;
    float* Ap = ws + ATMP_OFF + (size_t)(cam*NG + g) * 12;
    Ap[0] = u;  Ap[1] = v;  Ap[2] = ia; Ap[3] = ib;
    Ap[4] = id_; Ap[5] = o; Ap[6] = rgb[g*3+0]; Ap[7] = rgb[g*3+1];
    Ap[8] = rgb[g*3+2]; Ap[9] = 0.f; Ap[10] = 0.f; Ap[11] = 0.f;
}

// O(N^2) rank sort: barrier-free, 2048 threads. Each thread counts how many
// z's precede its own (stable tie-break by index), then scatters its 12-float
// record to B[rank].
__global__ __launch_bounds__(256) void rank_kernel(float* __restrict__ ws) {
    int idx = blockIdx.x * blockDim.x + threadIdx.x;
    if (idx >= NC * NG) return;
    int cam = idx >> 10;
    int g   = idx & (NG - 1);
    const float* z = ws + Z_OFF + cam*NG;   // cam is wave-uniform -> scalar loads
    float zi = z[g];
    int rank = 0;
    #pragma unroll 8
    for (int j = 0; j < NG; j++) {
        float zj = z[j];
        rank += (zj < zi) || (zj == zi && j < g);
    }
    const float4* src = (const float4*)(ws + ATMP_OFF + (size_t)(cam*NG + g) * 12);
    float4* dst = (float4*)(ws + B_OFF + (size_t)(cam*NG + rank) * 12);
    dst[0] = src[0]; dst[1] = src[1]; dst[2] = src[2];
}

// Render: block = 256 threads = 4 waves. Wave s composites depth-segment s
// (256 gaussians) for an 8x8 pixel tile (lane = pixel). Gaussian index is
// wave-uniform -> compiler emits scalar s_load for the 48B record; the hot
// loop has zero vector-memory / LDS traffic. Partials merged per pixel via
// the associative compositing law (C,T)+(C',T') = (C + T*C', T*T').
#define SEG 256

__global__ __launch_bounds__(256) void render_kernel(const float* __restrict__ ws,
                                                     float* __restrict__ out) {
    const int cam  = blockIdx.z;
    const int lane = threadIdx.x & 63;
    const int seg  = __builtin_amdgcn_readfirstlane(threadIdx.x >> 6);

    const float* B = ws + B_OFF + (size_t)cam * NG * 12 + (size_t)seg * SEG * 12;

    const int tx = blockIdx.x * 8 + (lane & 7);
    const int ty = blockIdx.y * 8 + (lane >> 3);
    const float pxl = (float)tx + 0.5f;
    const float pyl = (float)ty + 0.5f;

    float T = 1.f, cr = 0.f, cg = 0.f, cb = 0.f;

    #pragma unroll 4
    for (int i = 0; i < SEG; i++) {
        const float* gp = B + i * 12;
        float u  = gp[0], v  = gp[1], ia = gp[2], ib = gp[3];
        float id = gp[4], o  = gp[5], r  = gp[6], gg = gp[7], bb = gp[8];
        float dx = u - pxl;
        float dy = v - pyl;
        float sigma = 0.5f*(ia*dx*dx + id*dy*dy) + ib*dx*dy;
        float alpha = fminf(o * __expf(-sigma), ALPHA_MAX);
        alpha = (sigma >= 0.f && alpha > ALPHA_MIN) ? alpha : 0.f;
        float w = alpha * T;
        cr += w * r;
        cg += w * gg;
        cb += w * bb;
        T  -= alpha * T;
        if ((i & 31) == 31 && __all(T < 1e-4f)) break;
    }

    __shared__ float4 part[4][72];   // [seg][pixel], padded
    part[seg][lane] = make_float4(cr, cg, cb, T);
    __syncthreads();

    if (threadIdx.x < 64) {
        float4 c0 = part[0][lane];
        float Cr = c0.x, Cg = c0.y, Cb = c0.z, Tp = c0.w;
        #pragma unroll
        for (int s = 1; s < 4; s++) {
            float4 cs = part[s][lane];
            Cr += Tp * cs.x;
            Cg += Tp * cs.y;
            Cb += Tp * cs.z;
            Tp *= cs.w;
        }
        int p = ty * WW + tx;
        float* img = out + (size_t)cam * (HH*WW*3) + (size_t)p * 3;
        img[0] = Cr + Tp;           // bg = (1,1,1)
        img[1] = Cg + Tp;
        img[2] = Cb + Tp;
        out[(size_t)NC*HH*WW*3 + (size_t)cam*(HH*WW) + p] = 1.f - Tp;
    }
}

extern "C" void kernel_launch(void* const* d_in, const int* in_sizes, int n_in,
                              void* d_out, int out_size, void* d_ws, size_t ws_size,
                              hipStream_t stream) {
    const float* w2cs  = (const float*)d_in[0];
    const float* Ks    = (const float*)d_in[1];
    const float* xyz   = (const float*)d_in[2];
    const float* rgb   = (const float*)d_in[3];
    const float* opac  = (const float*)d_in[4];
    const float* scale = (const float*)d_in[5];
    const float* rot   = (const float*)d_in[6];
    float* out = (float*)d_out;
    float* ws  = (float*)d_ws;

    prep_kernel<<<dim3((NC*NG + 255)/256), 256, 0, stream>>>(w2cs, Ks, xyz, rgb, opac, scale, rot, ws);
    rank_kernel<<<dim3((NC*NG + 255)/256), 256, 0, stream>>>(ws);
    render_kernel<<<dim3(WW/8, HH/8, NC), 256, 0, stream>>>(ws, out);
}

// Round 3
// 118.883 us; speedup vs baseline: 1.8830x; 1.5362x over previous
//
#include <hip/hip_runtime.h>
#include <math.h>

#define NG 1024
#define NC 2
#define HH 224
#define WW 224
#define TILES_X 28
#define TILES_Y 28
#define EPS2D 0.3f
#define ALPHA_MIN (1.0f/255.0f)
#define ALPHA_MAX 0.999f

// Workspace layout (float units):
//   z     at Z_OFF    : NC*NG
//   Atmp  at ATMP_OFF : NC*NG*12 AoS (u,v,ia,ib,id,o,r,g,b,rx,ry,pad)
//   B     at B_OFF    : NC*NG*12 depth-sorted AoS, same layout
//   bbox  at BB_OFF   : NC*NG packed ints (tx0|tx1<<8|ty0<<16|ty1<<24), sorted order
#define Z_OFF    0
#define ATMP_OFF (NC*NG)
#define B_OFF    (ATMP_OFF + NC*NG*12)
#define BB_OFF   (B_OFF + NC*NG*12)

__global__ void prep_kernel(const float* __restrict__ w2cs, const float* __restrict__ Ks,
                            const float* __restrict__ xyz, const float* __restrict__ rgb,
                            const float* __restrict__ opac, const float* __restrict__ scale,
                            const float* __restrict__ rot, float* __restrict__ ws) {
    int idx = blockIdx.x * blockDim.x + threadIdx.x;
    if (idx >= NC * NG) return;
    int cam = idx >> 10;
    int g   = idx & (NG - 1);

    float qw = rot[g*4+0], qx = rot[g*4+1], qy = rot[g*4+2], qz = rot[g*4+3];
    float qn = rsqrtf(qw*qw + qx*qx + qy*qy + qz*qz);
    qw *= qn; qx *= qn; qy *= qn; qz *= qn;
    float r00 = 1.f - 2.f*(qy*qy + qz*qz), r01 = 2.f*(qx*qy - qw*qz), r02 = 2.f*(qx*qz + qw*qy);
    float r10 = 2.f*(qx*qy + qw*qz), r11 = 1.f - 2.f*(qx*qx + qz*qz), r12 = 2.f*(qy*qz - qw*qx);
    float r20 = 2.f*(qx*qz - qw*qy), r21 = 2.f*(qy*qz + qw*qx), r22 = 1.f - 2.f*(qx*qx + qy*qy);

    float sx = scale[g*3+0], sy = scale[g*3+1], sz = scale[g*3+2];
    float m00 = r00*sx, m01 = r01*sy, m02 = r02*sz;
    float m10 = r10*sx, m11 = r11*sy, m12 = r12*sz;
    float m20 = r20*sx, m21 = r21*sy, m22 = r22*sz;
    float c00 = m00*m00 + m01*m01 + m02*m02;
    float c01 = m00*m10 + m01*m11 + m02*m12;
    float c02 = m00*m20 + m01*m21 + m02*m22;
    float c11 = m10*m10 + m11*m11 + m12*m12;
    float c12 = m10*m20 + m11*m21 + m12*m22;
    float c22 = m20*m20 + m21*m21 + m22*m22;

    const float* vm = w2cs + cam*16;
    float R00 = vm[0],  R01 = vm[1],  R02 = vm[2],  t0 = vm[3];
    float R10 = vm[4],  R11 = vm[5],  R12 = vm[6],  t1 = vm[7];
    float R20 = vm[8],  R21 = vm[9],  R22 = vm[10], t2 = vm[11];

    float X = xyz[g*3], Y = xyz[g*3+1], Z = xyz[g*3+2];
    float px = R00*X + R01*Y + R02*Z + t0;
    float py = R10*X + R11*Y + R12*Z + t1;
    float pz = R20*X + R21*Y + R22*Z + t2;
    float rz = 1.f / pz;

    const float* Kc = Ks + cam*9;
    float fx = Kc[0], cx = Kc[2], fy = Kc[4], cy = Kc[5];
    float limx = 1.3f * (0.5f * (float)WW / fx);
    float limy = 1.3f * (0.5f * (float)HH / fy);
    float txc = pz * fminf(fmaxf(px*rz, -limx), limx);
    float tyc = pz * fminf(fmaxf(py*rz, -limy), limy);

    float v00 = R00*c00 + R01*c01 + R02*c02;
    float v01 = R00*c01 + R01*c11 + R02*c12;
    float v02 = R00*c02 + R01*c12 + R02*c22;
    float v10 = R10*c00 + R11*c01 + R12*c02;
    float v11 = R10*c01 + R11*c11 + R12*c12;
    float v12 = R10*c02 + R11*c12 + R12*c22;
    float v20 = R20*c00 + R21*c01 + R22*c02;
    float v21 = R20*c01 + R21*c11 + R22*c12;
    float v22 = R20*c02 + R21*c12 + R22*c22;
    float cc00 = v00*R00 + v01*R01 + v02*R02;
    float cc01 = v00*R10 + v01*R11 + v02*R12;
    float cc02 = v00*R20 + v01*R21 + v02*R22;
    float cc11 = v10*R10 + v11*R11 + v12*R12;
    float cc12 = v10*R20 + v11*R21 + v12*R22;
    float cc22 = v20*R20 + v21*R21 + v22*R22;

    float j00 = fx*rz, j02 = -fx*txc*rz*rz;
    float j11 = fy*rz, j12 = -fy*tyc*rz*rz;
    float a = j00*j00*cc00 + 2.f*j00*j02*cc02 + j02*j02*cc22 + EPS2D;
    float b = j00*j11*cc01 + j00*j12*cc02 + j02*j11*cc12 + j02*j12*cc22;
    float d = j11*j11*cc11 + 2.f*j11*j12*cc12 + j12*j12*cc22 + EPS2D;
    float det = a*d - b*b;

    bool valid = (pz > 0.01f) && (pz < 100.f) && (det > 0.f);
    float idet = valid ? (1.f / det) : 0.f;
    float ia  = d * idet;
    float ib  = -b * idet;
    float id_ = a * idet;
    float u = valid ? (fx*px*rz + cx) : 0.f;
    float v = valid ? (fy*py*rz + cy) : 0.f;
    float o = valid ? opac[g] : 0.f;

    // Exact support: contributes iff sigma < tau = ln(255*o). Bbox of that
    // ellipse: rx = sqrt(2*tau*a_cov), ry = sqrt(2*tau*d_cov). (conic is PD
    // for valid gaussians, so sigma>=0 everywhere; binning is exact.)
    float tau = __logf(255.f * o);
    float rxr = -1.f, ryr = -1.f;
    if (valid && tau > 0.f) {
        rxr = sqrtf(2.f * tau * a) + 0.01f;
        ryr = sqrtf(2.f * tau * d) + 0.01f;
    }

    ws[Z_OFF + cam*NG + g] = pz;
    float* Ap = ws + ATMP_OFF + (size_t)(cam*NG + g) * 12;
    Ap[0] = u;  Ap[1] = v;  Ap[2] = ia; Ap[3] = ib;
    Ap[4] = id_; Ap[5] = o; Ap[6] = rgb[g*3+0]; Ap[7] = rgb[g*3+1];
    Ap[8] = rgb[g*3+2]; Ap[9] = rxr; Ap[10] = ryr; Ap[11] = 0.f;
}

// O(N^2) rank sort + scatter of record and packed tile-bbox (sorted order).
__global__ __launch_bounds__(256) void rank_kernel(float* __restrict__ ws) {
    int idx = blockIdx.x * blockDim.x + threadIdx.x;
    if (idx >= NC * NG) return;
    int cam = idx >> 10;
    int g   = idx & (NG - 1);
    const float4* z4 = (const float4*)(ws + Z_OFF + cam*NG);
    float zi = ws[Z_OFF + cam*NG + g];
    int rank = 0;
    #pragma unroll 8
    for (int j = 0; j < NG/4; j++) {
        float4 zz = z4[j];
        int j4 = j*4;
        rank += (zz.x < zi) || (zz.x == zi && (j4  ) < g);
        rank += (zz.y < zi) || (zz.y == zi && (j4+1) < g);
        rank += (zz.z < zi) || (zz.z == zi && (j4+2) < g);
        rank += (zz.w < zi) || (zz.w == zi && (j4+3) < g);
    }
    const float4* src = (const float4*)(ws + ATMP_OFF + (size_t)(cam*NG + g) * 12);
    float4 s0 = src[0], s1 = src[1], s2 = src[2];
    float4* dst = (float4*)(ws + B_OFF + (size_t)(cam*NG + rank) * 12);
    dst[0] = s0; dst[1] = s1; dst[2] = s2;

    // bbox from u=s0.x, v=s0.y, rx=s2.y, ry=s2.z
    unsigned int packed = 0xFFFFFFFFu;   // empty
    float rx = s2.y, ry = s2.z;
    if (rx > 0.f) {
        int xmin = (int)ceilf (s0.x - rx - 0.5f);
        int xmax = (int)floorf(s0.x + rx - 0.5f);
        int ymin = (int)ceilf (s0.y - ry - 0.5f);
        int ymax = (int)floorf(s0.y + ry - 0.5f);
        xmin = max(xmin, 0); xmax = min(xmax, WW-1);
        ymin = max(ymin, 0); ymax = min(ymax, HH-1);
        if (xmin <= xmax && ymin <= ymax) {
            packed = (unsigned)(xmin>>3) | ((unsigned)(xmax>>3)<<8)
                   | ((unsigned)(ymin>>3)<<16) | ((unsigned)(ymax>>3)<<24);
        }
    }
    ((unsigned int*)(ws + BB_OFF))[cam*NG + rank] = packed;
}

// One wave per 8x8 tile: ballot-compact this tile's depth-ordered gaussian
// list into LDS, then composite only the list (scalar-load records).
__global__ __launch_bounds__(64) void render_kernel(const float* __restrict__ ws,
                                                    float* __restrict__ out) {
    const int cam = blockIdx.z;
    const int TX = blockIdx.x, TY = blockIdx.y;
    const int lane = threadIdx.x;

    __shared__ int list[NG];
    const unsigned int* bb = (const unsigned int*)(ws + BB_OFF) + cam*NG;

    int nlist = 0;
    #pragma unroll 4
    for (int k = 0; k < NG/64; k++) {
        int gid = k*64 + lane;
        unsigned int pb = bb[gid];
        int tx0 = pb & 255, tx1 = (pb>>8) & 255;
        int ty0 = (pb>>16) & 255, ty1 = (pb>>24) & 255;
        bool hit = (TX >= tx0) && (TX <= tx1) && (TY >= ty0) && (TY <= ty1);
        unsigned long long m = __ballot(hit);
        if (hit) {
            int pos = nlist + __popcll(m & ((1ull << lane) - 1ull));
            list[pos] = gid;
        }
        nlist += __popcll(m);
    }
    // wave-level only; no __syncthreads needed (single wave per block)

    const float* Bc = ws + B_OFF + (size_t)cam * NG * 12;
    const float pxl = (float)(TX*8 + (lane & 7)) + 0.5f;
    const float pyl = (float)(TY*8 + (lane >> 3)) + 0.5f;

    float T = 1.f, cr = 0.f, cg = 0.f, cb = 0.f;

    for (int i = 0; i < nlist; i++) {
        int gid = __builtin_amdgcn_readfirstlane(list[i]);
        const float* gp = Bc + gid * 12;
        float u  = gp[0], v  = gp[1], ia = gp[2], ib = gp[3];
        float id = gp[4], o  = gp[5], r  = gp[6], gg = gp[7], bbv = gp[8];
        float dx = u - pxl;
        float dy = v - pyl;
        float sigma = 0.5f*(ia*dx*dx + id*dy*dy) + ib*dx*dy;
        float alpha = fminf(o * __expf(-sigma), ALPHA_MAX);
        alpha = (sigma >= 0.f && alpha > ALPHA_MIN) ? alpha : 0.f;
        float w = alpha * T;
        cr += w * r;
        cg += w * gg;
        cb += w * bbv;
        T  -= alpha * T;
        if ((i & 7) == 7 && __all(T < 1e-4f)) break;
    }

    int p = (TY*8 + (lane >> 3)) * WW + TX*8 + (lane & 7);
    float* img = out + (size_t)cam * (HH*WW*3) + (size_t)p * 3;
    img[0] = cr + T;            // bg = (1,1,1)
    img[1] = cg + T;
    img[2] = cb + T;
    out[(size_t)NC*HH*WW*3 + (size_t)cam*(HH*WW) + p] = 1.f - T;
}

extern "C" void kernel_launch(void* const* d_in, const int* in_sizes, int n_in,
                              void* d_out, int out_size, void* d_ws, size_t ws_size,
                              hipStream_t stream) {
    const float* w2cs  = (const float*)d_in[0];
    const float* Ks    = (const float*)d_in[1];
    const float* xyz   = (const float*)d_in[2];
    const float* rgb   = (const float*)d_in[3];
    const float* opac  = (const float*)d_in[4];
    const float* scale = (const float*)d_in[5];
    const float* rot   = (const float*)d_in[6];
    float* out = (float*)d_out;
    float* ws  = (float*)d_ws;

    prep_kernel<<<dim3((NC*NG + 255)/256), 256, 0, stream>>>(w2cs, Ks, xyz, rgb, opac, scale, rot, ws);
    rank_kernel<<<dim3((NC*NG + 255)/256), 256, 0, stream>>>(ws);
    render_kernel<<<dim3(TILES_X, TILES_Y, NC), 64, 0, stream>>>(ws, out);
}

// Round 4
// 109.301 us; speedup vs baseline: 2.0480x; 1.0877x over previous
//
#include <hip/hip_runtime.h>
#include <math.h>

#define NG 1024
#define NC 2
#define HH 224
#define WW 224
#define TILES_X 28
#define TILES_Y 28
#define EPS2D 0.3f
#define ALPHA_MIN (1.0f/255.0f)
#define ALPHA_MAX 0.999f

// Workspace (float units):
//   B    at B_OFF : NC*NG*12, depth-sorted AoS records (u,v,ia,ib | id,o,r,g | b,0,0,0)
//   bbox at BB_OFF: NC*NG packed uints (tile tx0|tx1<<8|ty0<<16|ty1<<24), sorted order
#define B_OFF  0
#define BB_OFF (NC*NG*12)

// One block per camera, one thread per gaussian. Prep math -> z to LDS ->
// O(N) rank per thread (LDS broadcast reads) -> scatter record+bbox directly
// to depth-sorted position. Replaces two kernels and the Atmp round-trip.
__global__ __launch_bounds__(1024) void prep_rank_kernel(
        const float* __restrict__ w2cs, const float* __restrict__ Ks,
        const float* __restrict__ xyz, const float* __restrict__ rgb,
        const float* __restrict__ opac, const float* __restrict__ scale,
        const float* __restrict__ rot, float* __restrict__ ws) {
    const int cam = blockIdx.x;
    const int g   = threadIdx.x;

    float qw = rot[g*4+0], qx = rot[g*4+1], qy = rot[g*4+2], qz = rot[g*4+3];
    float qn = rsqrtf(qw*qw + qx*qx + qy*qy + qz*qz);
    qw *= qn; qx *= qn; qy *= qn; qz *= qn;
    float r00 = 1.f - 2.f*(qy*qy + qz*qz), r01 = 2.f*(qx*qy - qw*qz), r02 = 2.f*(qx*qz + qw*qy);
    float r10 = 2.f*(qx*qy + qw*qz), r11 = 1.f - 2.f*(qx*qx + qz*qz), r12 = 2.f*(qy*qz - qw*qx);
    float r20 = 2.f*(qx*qz - qw*qy), r21 = 2.f*(qy*qz + qw*qx), r22 = 1.f - 2.f*(qx*qx + qy*qy);

    float sx = scale[g*3+0], sy = scale[g*3+1], sz = scale[g*3+2];
    float m00 = r00*sx, m01 = r01*sy, m02 = r02*sz;
    float m10 = r10*sx, m11 = r11*sy, m12 = r12*sz;
    float m20 = r20*sx, m21 = r21*sy, m22 = r22*sz;
    float c00 = m00*m00 + m01*m01 + m02*m02;
    float c01 = m00*m10 + m01*m11 + m02*m12;
    float c02 = m00*m20 + m01*m21 + m02*m22;
    float c11 = m10*m10 + m11*m11 + m12*m12;
    float c12 = m10*m20 + m11*m21 + m12*m22;
    float c22 = m20*m20 + m21*m21 + m22*m22;

    const float* vm = w2cs + cam*16;
    float R00 = vm[0],  R01 = vm[1],  R02 = vm[2],  t0 = vm[3];
    float R10 = vm[4],  R11 = vm[5],  R12 = vm[6],  t1 = vm[7];
    float R20 = vm[8],  R21 = vm[9],  R22 = vm[10], t2 = vm[11];

    float X = xyz[g*3], Y = xyz[g*3+1], Z = xyz[g*3+2];
    float px = R00*X + R01*Y + R02*Z + t0;
    float py = R10*X + R11*Y + R12*Z + t1;
    float pz = R20*X + R21*Y + R22*Z + t2;
    float rz = 1.f / pz;

    const float* Kc = Ks + cam*9;
    float fx = Kc[0], cx = Kc[2], fy = Kc[4], cy = Kc[5];
    float limx = 1.3f * (0.5f * (float)WW / fx);
    float limy = 1.3f * (0.5f * (float)HH / fy);
    float txc = pz * fminf(fmaxf(px*rz, -limx), limx);
    float tyc = pz * fminf(fmaxf(py*rz, -limy), limy);

    float v00 = R00*c00 + R01*c01 + R02*c02;
    float v01 = R00*c01 + R01*c11 + R02*c12;
    float v02 = R00*c02 + R01*c12 + R02*c22;
    float v10 = R10*c00 + R11*c01 + R12*c02;
    float v11 = R10*c01 + R11*c11 + R12*c12;
    float v12 = R10*c02 + R11*c12 + R12*c22;
    float v20 = R20*c00 + R21*c01 + R22*c02;
    float v21 = R20*c01 + R21*c11 + R22*c12;
    float v22 = R20*c02 + R21*c12 + R22*c22;
    float cc00 = v00*R00 + v01*R01 + v02*R02;
    float cc01 = v00*R10 + v01*R11 + v02*R12;
    float cc02 = v00*R20 + v01*R21 + v02*R22;
    float cc11 = v10*R10 + v11*R11 + v12*R12;
    float cc12 = v10*R20 + v11*R21 + v12*R22;
    float cc22 = v20*R20 + v21*R21 + v22*R22;

    float j00 = fx*rz, j02 = -fx*txc*rz*rz;
    float j11 = fy*rz, j12 = -fy*tyc*rz*rz;
    float a = j00*j00*cc00 + 2.f*j00*j02*cc02 + j02*j02*cc22 + EPS2D;
    float b = j00*j11*cc01 + j00*j12*cc02 + j02*j11*cc12 + j02*j12*cc22;
    float d = j11*j11*cc11 + 2.f*j11*j12*cc12 + j12*j12*cc22 + EPS2D;
    float det = a*d - b*b;

    bool valid = (pz > 0.01f) && (pz < 100.f) && (det > 0.f);
    float idet = valid ? (1.f / det) : 0.f;
    float ia  = d * idet;
    float ib  = -b * idet;
    float id_ = a * idet;
    float u = valid ? (fx*px*rz + cx) : 0.f;
    float v = valid ? (fy*py*rz + cy) : 0.f;
    float o = valid ? opac[g] : 0.f;

    // rank by z (stable): LDS broadcast compares
    __shared__ float zsh[NG];
    zsh[g] = pz;
    __syncthreads();
    int rank = 0;
    const float4* z4 = (const float4*)zsh;
    #pragma unroll 8
    for (int j = 0; j < NG/4; j++) {
        float4 zz = z4[j];
        int j4 = j*4;
        rank += (zz.x < pz) || (zz.x == pz && (j4  ) < g);
        rank += (zz.y < pz) || (zz.y == pz && (j4+1) < g);
        rank += (zz.z < pz) || (zz.z == pz && (j4+2) < g);
        rank += (zz.w < pz) || (zz.w == pz && (j4+3) < g);
    }

    float4* dst = (float4*)(ws + B_OFF + (size_t)(cam*NG + rank) * 12);
    dst[0] = make_float4(u, v, ia, ib);
    dst[1] = make_float4(id_, o, rgb[g*3+0], rgb[g*3+1]);
    dst[2] = make_float4(rgb[g*3+2], 0.f, 0.f, 0.f);

    // Exact support bbox: contributes iff sigma < tau = ln(255*o); ellipse
    // x/y half-extents sqrt(2*tau*a), sqrt(2*tau*d) (a,d are cov entries).
    unsigned int packed = 0xFFFFFFFFu;   // empty sentinel (tx0=255 never hits)
    float tau = __logf(255.f * o);
    if (valid && tau > 0.f) {
        float rx = sqrtf(2.f * tau * a) + 0.01f;
        float ry = sqrtf(2.f * tau * d) + 0.01f;
        int xmin = max((int)ceilf (u - rx - 0.5f), 0);
        int xmax = min((int)floorf(u + rx - 0.5f), WW-1);
        int ymin = max((int)ceilf (v - ry - 0.5f), 0);
        int ymax = min((int)floorf(v + ry - 0.5f), HH-1);
        if (xmin <= xmax && ymin <= ymax) {
            packed = (unsigned)(xmin>>3) | ((unsigned)(xmax>>3)<<8)
                   | ((unsigned)(ymin>>3)<<16) | ((unsigned)(ymax>>3)<<24);
        }
    }
    ((unsigned int*)(ws + BB_OFF))[cam*NG + rank] = packed;
}

// Block = 256 threads = 4 waves per 8x8 tile. Wave s ballot-compacts and
// composites depth-segment s (256 sorted gaussians) filtered to this tile;
// list entries broadcast via v_readlane (not per-iter LDS reads); partials
// merged per pixel via (C,T)+(C',T') = (C + T*C', T*T').
__global__ __launch_bounds__(256) void render_kernel(const float* __restrict__ ws,
                                                     float* __restrict__ out) {
    const int cam  = blockIdx.z;
    const int TX = blockIdx.x, TY = blockIdx.y;
    const int lane = threadIdx.x & 63;
    const int seg  = __builtin_amdgcn_readfirstlane(threadIdx.x >> 6);

    __shared__ int list[4][256];
    __shared__ float4 part[4][64];

    const unsigned int* bb = (const unsigned int*)(ws + BB_OFF) + cam*NG + seg*256;
    int nlist = 0;
    #pragma unroll
    for (int k = 0; k < 4; k++) {
        int gi = k*64 + lane;
        unsigned int pb = bb[gi];
        int tx0 = pb & 255, tx1 = (pb>>8) & 255;
        int ty0 = (pb>>16) & 255, ty1 = (pb>>24) & 255;
        bool hit = (TX >= tx0) && (TX <= tx1) && (TY >= ty0) && (TY <= ty1);
        unsigned long long m = __ballot(hit);
        if (hit) {
            int pos = nlist + __popcll(m & ((1ull << lane) - 1ull));
            list[seg][pos] = seg*256 + gi;
        }
        nlist += __popcll(m);
    }

    const float* Bc = ws + B_OFF + (size_t)cam * NG * 12;
    const float pxl = (float)(TX*8 + (lane & 7)) + 0.5f;
    const float pyl = (float)(TY*8 + (lane >> 3)) + 0.5f;

    float T = 1.f, cr = 0.f, cg = 0.f, cb = 0.f;

    for (int ci = 0; ci < nlist; ci += 64) {
        int ent = list[seg][ci + lane];            // <=256 bound, safe over-read
        int cnt = min(64, nlist - ci);
        for (int j = 0; j < cnt; j++) {
            int gid = __builtin_amdgcn_readlane(ent, j);   // wave-uniform
            const float* gp = Bc + gid * 12;               // -> s_load record
            float u  = gp[0], v  = gp[1], ia = gp[2], ib = gp[3];
            float id = gp[4], o  = gp[5], rr = gp[6], gg = gp[7], bv = gp[8];
            float dx = u - pxl;
            float dy = v - pyl;
            float sigma = 0.5f*(ia*dx*dx + id*dy*dy) + ib*dx*dy;
            float alpha = fminf(o * __expf(-sigma), ALPHA_MAX);
            alpha = (sigma >= 0.f && alpha > ALPHA_MIN) ? alpha : 0.f;
            float w = alpha * T;
            cr += w * rr;
            cg += w * gg;
            cb += w * bv;
            T  -= alpha * T;
        }
        if (__all(T < 1e-4f)) break;   // this wave's segment transmittance
    }

    part[seg][lane] = make_float4(cr, cg, cb, T);
    __syncthreads();

    if (threadIdx.x < 64) {
        float4 c0 = part[0][lane];
        float Cr = c0.x, Cg = c0.y, Cb = c0.z, Tp = c0.w;
        #pragma unroll
        for (int s = 1; s < 4; s++) {
            float4 cs = part[s][lane];
            Cr += Tp * cs.x;
            Cg += Tp * cs.y;
            Cb += Tp * cs.z;
            Tp *= cs.w;
        }
        int p = (TY*8 + (lane >> 3)) * WW + TX*8 + (lane & 7);
        float* img = out + (size_t)cam * (HH*WW*3) + (size_t)p * 3;
        img[0] = Cr + Tp;           // bg = (1,1,1)
        img[1] = Cg + Tp;
        img[2] = Cb + Tp;
        out[(size_t)NC*HH*WW*3 + (size_t)cam*(HH*WW) + p] = 1.f - Tp;
    }
}

extern "C" void kernel_launch(void* const* d_in, const int* in_sizes, int n_in,
                              void* d_out, int out_size, void* d_ws, size_t ws_size,
                              hipStream_t stream) {
    const float* w2cs  = (const float*)d_in[0];
    const float* Ks    = (const float*)d_in[1];
    const float* xyz   = (const float*)d_in[2];
    const float* rgb   = (const float*)d_in[3];
    const float* opac  = (const float*)d_in[4];
    const float* scale = (const float*)d_in[5];
    const float* rot   = (const float*)d_in[6];
    float* out = (float*)d_out;
    float* ws  = (float*)d_ws;

    prep_rank_kernel<<<dim3(NC), 1024, 0, stream>>>(w2cs, Ks, xyz, rgb, opac, scale, rot, ws);
    render_kernel<<<dim3(TILES_X, TILES_Y, NC), 256, 0, stream>>>(ws, out);
}

// Round 5
// 107.898 us; speedup vs baseline: 2.0747x; 1.0130x over previous
//
#include <hip/hip_runtime.h>
#include <math.h>

#define NG 1024
#define NC 2
#define HH 224
#define WW 224
#define TILES_X 28
#define TILES_Y 28
#define EPS2D 0.3f
#define ALPHA_MIN (1.0f/255.0f)
#define ALPHA_MAX 0.999f

// Workspace layout (float units):
//   z     at Z_OFF    : NC*NG
//   Atmp  at ATMP_OFF : NC*NG*12 AoS (u,v,ia,ib | id,o,r,g | b,rx,ry,pad)
//   B     at B_OFF    : NC*NG*12 depth-sorted AoS, same layout
//   bbox  at BB_OFF   : NC*NG packed uints (tile tx0|tx1<<8|ty0<<16|ty1<<24), sorted order
#define Z_OFF    0
#define ATMP_OFF (NC*NG)
#define B_OFF    (ATMP_OFF + NC*NG*12)
#define BB_OFF   (B_OFF + NC*NG*12)

__global__ void prep_kernel(const float* __restrict__ w2cs, const float* __restrict__ Ks,
                            const float* __restrict__ xyz, const float* __restrict__ rgb,
                            const float* __restrict__ opac, const float* __restrict__ scale,
                            const float* __restrict__ rot, float* __restrict__ ws) {
    int idx = blockIdx.x * blockDim.x + threadIdx.x;
    if (idx >= NC * NG) return;
    int cam = idx >> 10;
    int g   = idx & (NG - 1);

    float qw = rot[g*4+0], qx = rot[g*4+1], qy = rot[g*4+2], qz = rot[g*4+3];
    float qn = rsqrtf(qw*qw + qx*qx + qy*qy + qz*qz);
    qw *= qn; qx *= qn; qy *= qn; qz *= qn;
    float r00 = 1.f - 2.f*(qy*qy + qz*qz), r01 = 2.f*(qx*qy - qw*qz), r02 = 2.f*(qx*qz + qw*qy);
    float r10 = 2.f*(qx*qy + qw*qz), r11 = 1.f - 2.f*(qx*qx + qz*qz), r12 = 2.f*(qy*qz - qw*qx);
    float r20 = 2.f*(qx*qz - qw*qy), r21 = 2.f*(qy*qz + qw*qx), r22 = 1.f - 2.f*(qx*qx + qy*qy);

    float sx = scale[g*3+0], sy = scale[g*3+1], sz = scale[g*3+2];
    float m00 = r00*sx, m01 = r01*sy, m02 = r02*sz;
    float m10 = r10*sx, m11 = r11*sy, m12 = r12*sz;
    float m20 = r20*sx, m21 = r21*sy, m22 = r22*sz;
    float c00 = m00*m00 + m01*m01 + m02*m02;
    float c01 = m00*m10 + m01*m11 + m02*m12;
    float c02 = m00*m20 + m01*m21 + m02*m22;
    float c11 = m10*m10 + m11*m11 + m12*m12;
    float c12 = m10*m20 + m11*m21 + m12*m22;
    float c22 = m20*m20 + m21*m21 + m22*m22;

    const float* vm = w2cs + cam*16;
    float R00 = vm[0],  R01 = vm[1],  R02 = vm[2],  t0 = vm[3];
    float R10 = vm[4],  R11 = vm[5],  R12 = vm[6],  t1 = vm[7];
    float R20 = vm[8],  R21 = vm[9],  R22 = vm[10], t2 = vm[11];

    float X = xyz[g*3], Y = xyz[g*3+1], Z = xyz[g*3+2];
    float px = R00*X + R01*Y + R02*Z + t0;
    float py = R10*X + R11*Y + R12*Z + t1;
    float pz = R20*X + R21*Y + R22*Z + t2;
    float rz = 1.f / pz;

    const float* Kc = Ks + cam*9;
    float fx = Kc[0], cx = Kc[2], fy = Kc[4], cy = Kc[5];
    float limx = 1.3f * (0.5f * (float)WW / fx);
    float limy = 1.3f * (0.5f * (float)HH / fy);
    float txc = pz * fminf(fmaxf(px*rz, -limx), limx);
    float tyc = pz * fminf(fmaxf(py*rz, -limy), limy);

    float v00 = R00*c00 + R01*c01 + R02*c02;
    float v01 = R00*c01 + R01*c11 + R02*c12;
    float v02 = R00*c02 + R01*c12 + R02*c22;
    float v10 = R10*c00 + R11*c01 + R12*c02;
    float v11 = R10*c01 + R11*c11 + R12*c12;
    float v12 = R10*c02 + R11*c12 + R12*c22;
    float v20 = R20*c00 + R21*c01 + R22*c02;
    float v21 = R20*c01 + R21*c11 + R22*c12;
    float v22 = R20*c02 + R21*c12 + R22*c22;
    float cc00 = v00*R00 + v01*R01 + v02*R02;
    float cc01 = v00*R10 + v01*R11 + v02*R12;
    float cc02 = v00*R20 + v01*R21 + v02*R22;
    float cc11 = v10*R10 + v11*R11 + v12*R12;
    float cc12 = v10*R20 + v11*R21 + v12*R22;
    float cc22 = v20*R20 + v21*R21 + v22*R22;

    float j00 = fx*rz, j02 = -fx*txc*rz*rz;
    float j11 = fy*rz, j12 = -fy*tyc*rz*rz;
    float a = j00*j00*cc00 + 2.f*j00*j02*cc02 + j02*j02*cc22 + EPS2D;
    float b = j00*j11*cc01 + j00*j12*cc02 + j02*j11*cc12 + j02*j12*cc22;
    float d = j11*j11*cc11 + 2.f*j11*j12*cc12 + j12*j12*cc22 + EPS2D;
    float det = a*d - b*b;

    bool valid = (pz > 0.01f) && (pz < 100.f) && (det > 0.f);
    float idet = valid ? (1.f / det) : 0.f;
    float ia  = d * idet;
    float ib  = -b * idet;
    float id_ = a * idet;
    float u = valid ? (fx*px*rz + cx) : 0.f;
    float v = valid ? (fy*py*rz + cy) : 0.f;
    float o = valid ? opac[g] : 0.f;

    // Exact support: contributes iff sigma < tau = ln(255*o). Ellipse bbox
    // half-extents rx = sqrt(2*tau*a), ry = sqrt(2*tau*d) (a,d = cov2d diag).
    float tau = __logf(255.f * o);
    float rxr = -1.f, ryr = -1.f;
    if (valid && tau > 0.f) {
        rxr = sqrtf(2.f * tau * a) + 0.01f;
        ryr = sqrtf(2.f * tau * d) + 0.01f;
    }

    ws[Z_OFF + cam*NG + g] = pz;
    float4* Ap = (float4*)(ws + ATMP_OFF + (size_t)(cam*NG + g) * 12);
    Ap[0] = make_float4(u, v, ia, ib);
    Ap[1] = make_float4(id_, o, rgb[g*3+0], rgb[g*3+1]);
    Ap[2] = make_float4(rgb[g*3+2], rxr, ryr, 0.f);
}

// O(N) rank per thread over the L1-resident 4KB z array (8 blocks x 256),
// then scatter record + packed tile-bbox to the depth-sorted position.
__global__ __launch_bounds__(256) void rank_kernel(float* __restrict__ ws) {
    int idx = blockIdx.x * blockDim.x + threadIdx.x;
    if (idx >= NC * NG) return;
    int cam = idx >> 10;
    int g   = idx & (NG - 1);
    const float4* z4 = (const float4*)(ws + Z_OFF + cam*NG);
    float zi = ws[Z_OFF + cam*NG + g];
    int rank = 0;
    #pragma unroll 8
    for (int j = 0; j < NG/4; j++) {
        float4 zz = z4[j];
        int j4 = j*4;
        rank += (zz.x < zi) || (zz.x == zi && (j4  ) < g);
        rank += (zz.y < zi) || (zz.y == zi && (j4+1) < g);
        rank += (zz.z < zi) || (zz.z == zi && (j4+2) < g);
        rank += (zz.w < zi) || (zz.w == zi && (j4+3) < g);
    }
    const float4* src = (const float4*)(ws + ATMP_OFF + (size_t)(cam*NG + g) * 12);
    float4 s0 = src[0], s1 = src[1], s2 = src[2];
    float4* dst = (float4*)(ws + B_OFF + (size_t)(cam*NG + rank) * 12);
    dst[0] = s0; dst[1] = s1; dst[2] = s2;

    // bbox from u=s0.x, v=s0.y, rx=s2.y, ry=s2.z
    unsigned int packed = 0xFFFFFFFFu;   // empty sentinel (tx0=255 never hits)
    float rx = s2.y, ry = s2.z;
    if (rx > 0.f) {
        int xmin = max((int)ceilf (s0.x - rx - 0.5f), 0);
        int xmax = min((int)floorf(s0.x + rx - 0.5f), WW-1);
        int ymin = max((int)ceilf (s0.y - ry - 0.5f), 0);
        int ymax = min((int)floorf(s0.y + ry - 0.5f), HH-1);
        if (xmin <= xmax && ymin <= ymax) {
            packed = (unsigned)(xmin>>3) | ((unsigned)(xmax>>3)<<8)
                   | ((unsigned)(ymin>>3)<<16) | ((unsigned)(ymax>>3)<<24);
        }
    }
    ((unsigned int*)(ws + BB_OFF))[cam*NG + rank] = packed;
}

// Block = 256 threads = 4 waves per 8x8 tile. Wave s ballot-compacts and
// composites depth-segment s (256 sorted gaussians) filtered to this tile;
// list entries broadcast via v_readlane; partials merged per pixel via the
// associative compositing law (C,T)+(C',T') = (C + T*C', T*T').
__global__ __launch_bounds__(256) void render_kernel(const float* __restrict__ ws,
                                                     float* __restrict__ out) {
    const int cam  = blockIdx.z;
    const int TX = blockIdx.x, TY = blockIdx.y;
    const int lane = threadIdx.x & 63;
    const int seg  = __builtin_amdgcn_readfirstlane(threadIdx.x >> 6);

    __shared__ int list[4][256];
    __shared__ float4 part[4][64];

    const unsigned int* bb = (const unsigned int*)(ws + BB_OFF) + cam*NG + seg*256;
    int nlist = 0;
    #pragma unroll
    for (int k = 0; k < 4; k++) {
        int gi = k*64 + lane;
        unsigned int pb = bb[gi];
        int tx0 = pb & 255, tx1 = (pb>>8) & 255;
        int ty0 = (pb>>16) & 255, ty1 = (pb>>24) & 255;
        bool hit = (TX >= tx0) && (TX <= tx1) && (TY >= ty0) && (TY <= ty1);
        unsigned long long m = __ballot(hit);
        if (hit) {
            int pos = nlist + __popcll(m & ((1ull << lane) - 1ull));
            list[seg][pos] = seg*256 + gi;
        }
        nlist += __popcll(m);
    }

    const float* Bc = ws + B_OFF + (size_t)cam * NG * 12;
    const float pxl = (float)(TX*8 + (lane & 7)) + 0.5f;
    const float pyl = (float)(TY*8 + (lane >> 3)) + 0.5f;

    float T = 1.f, cr = 0.f, cg = 0.f, cb = 0.f;

    for (int ci = 0; ci < nlist; ci += 64) {
        int ent = list[seg][ci + lane];            // <=256 bound, safe over-read
        int cnt = min(64, nlist - ci);
        for (int j = 0; j < cnt; j++) {
            int gid = __builtin_amdgcn_readlane(ent, j);   // wave-uniform
            const float* gp = Bc + gid * 12;               // -> s_load record
            float u  = gp[0], v  = gp[1], ia = gp[2], ib = gp[3];
            float id = gp[4], o  = gp[5], rr = gp[6], gg = gp[7], bv = gp[8];
            float dx = u - pxl;
            float dy = v - pyl;
            float sigma = 0.5f*(ia*dx*dx + id*dy*dy) + ib*dx*dy;
            float alpha = fminf(o * __expf(-sigma), ALPHA_MAX);
            alpha = (sigma >= 0.f && alpha > ALPHA_MIN) ? alpha : 0.f;
            float w = alpha * T;
            cr += w * rr;
            cg += w * gg;
            cb += w * bv;
            T  -= alpha * T;
        }
        if (__all(T < 1e-4f)) break;   // this wave's segment transmittance
    }

    part[seg][lane] = make_float4(cr, cg, cb, T);
    __syncthreads();

    if (threadIdx.x < 64) {
        float4 c0 = part[0][lane];
        float Cr = c0.x, Cg = c0.y, Cb = c0.z, Tp = c0.w;
        #pragma unroll
        for (int s = 1; s < 4; s++) {
            float4 cs = part[s][lane];
            Cr += Tp * cs.x;
            Cg += Tp * cs.y;
            Cb += Tp * cs.z;
            Tp *= cs.w;
        }
        int p = (TY*8 + (lane >> 3)) * WW + TX*8 + (lane & 7);
        float* img = out + (size_t)cam * (HH*WW*3) + (size_t)p * 3;
        img[0] = Cr + Tp;           // bg = (1,1,1)
        img[1] = Cg + Tp;
        img[2] = Cb + Tp;
        out[(size_t)NC*HH*WW*3 + (size_t)cam*(HH*WW) + p] = 1.f - Tp;
    }
}

extern "C" void kernel_launch(void* const* d_in, const int* in_sizes, int n_in,
                              void* d_out, int out_size, void* d_ws, size_t ws_size,
                              hipStream_t stream) {
    const float* w2cs  = (const float*)d_in[0];
    const float* Ks    = (const float*)d_in[1];
    const float* xyz   = (const float*)d_in[2];
    const float* rgb   = (const float*)d_in[3];
    const float* opac  = (const float*)d_in[4];
    const float* scale = (const float*)d_in[5];
    const float* rot   = (const float*)d_in[6];
    float* out = (float*)d_out;
    float* ws  = (float*)d_ws;

    prep_kernel<<<dim3((NC*NG + 255)/256), 256, 0, stream>>>(w2cs, Ks, xyz, rgb, opac, scale, rot, ws);
    rank_kernel<<<dim3((NC*NG + 255)/256), 256, 0, stream>>>(ws);
    render_kernel<<<dim3(TILES_X, TILES_Y, NC), 256, 0, stream>>>(ws, out);
}